// Round 5
// baseline (117.618 us; speedup 1.0000x reference)
//
#include <hip/hip_runtime.h>
#include <math.h>

#define TPB   256
#define TILES 4
#define SPB   (TILES * TPB)   // 1024 samples per block

#define GLOBAL_AS __attribute__((address_space(1)))
#define LDS_AS    __attribute__((address_space(3)))

// Ortho term for one sample — UNCHANGED from the R4-passing kernel
// (absmax 24576 vs threshold 33096; do not perturb).
// fp32 throughout except detW (fp64): det has catastrophic cancellation and
// sigma_min feeds (sigma+eps)^-2 ~ 1e12 which dominates the loss.
__device__ __forceinline__ void sample_ortho(const float4 t0, const float4 t1,
                                             const float4 t2, double& ortho)
{
    float w00 = t0.x, w01 = t0.y, w02 = t0.z;
    float w10 = t1.x, w11 = t1.y, w12 = t1.z;
    float w20 = t2.x, w21 = t2.y, w22 = t2.z;

    float A00 = w00*w00 + w10*w10 + w20*w20;
    float A11 = w01*w01 + w11*w11 + w21*w21;
    float A22 = w02*w02 + w12*w12 + w22*w22;
    float A01 = w00*w01 + w10*w11 + w20*w21;
    float A02 = w00*w02 + w10*w12 + w20*w22;
    float A12 = w01*w02 + w11*w12 + w21*w22;

    float I1 = A00 + A11 + A22;
    float I2 = (A00*A11 - A01*A01) + (A00*A22 - A02*A02) + (A11*A22 - A12*A12);

    double dw = (double)w00 * ((double)w11 * (double)w22 - (double)w12 * (double)w21)
              - (double)w01 * ((double)w10 * (double)w22 - (double)w12 * (double)w20)
              + (double)w02 * ((double)w10 * (double)w21 - (double)w11 * (double)w20);
    float I3 = (float)(dw * dw);   // det(A) >= 0

    float lam = (I2 > 0.f) ? I3 / I2 : 0.f;
    #pragma unroll
    for (int it = 0; it < 6; ++it) {
        float q = (lam - I1) * lam + I2;
        lam = (q > 0.f) ? I3 / q : lam;
    }
    if (lam < 0.f) lam = 0.f;

    float S = I1 - lam;
    float P = (lam - I1) * lam + I2;
    float disc = S * S - 4.f * P;
    disc = (disc > 0.f) ? sqrtf(disc) : 0.f;
    float l1 = 0.5f * (S + disc); if (l1 < 0.f) l1 = 0.f;
    float l2 = 0.5f * (S - disc); if (l2 < 0.f) l2 = 0.f;

    float s1 = sqrtf(l1)  + 1e-6f;
    float s2 = sqrtf(l2)  + 1e-6f;
    float s3 = sqrtf(lam) + 1e-6f;
    float q1 = s1 * s1, q2 = s2 * s2, q3 = s3 * s3;
    float inv = 1.f / (q1 * q2 * q3);
    ortho += (double)((q1 + q2 + q3) + inv * (q2 * q3 + q1 * q3 + q1 * q2) - 6.f);
}

__global__ __launch_bounds__(256) void theta_loss_main(
    const float4* __restrict__ theta4,
    const float4* __restrict__ affine4,
    double* __restrict__ partial, int n)
{
    __shared__ float4 ldsT[SPB * 3];   // 48 KB theta tile (3 blocks/CU)

    const int t  = threadIdx.x;
    const int w  = t >> 6;             // wave id (0..3)
    const int n4 = n * 3;
    const int base4 = blockIdx.x * (SPB * 3);   // float4 index of block start

    // ---- 1) async-stage theta: 12 x 16B global_load_lds per thread ----
    // LDS dest is wave-uniform base + lane*16 (HW rule); our layout
    // ldsT[k*TPB + w*64 + lane] matches exactly (contiguous per wave).
    #pragma unroll
    for (int k = 0; k < 12; ++k) {
        int j = base4 + k * TPB + t;
        if (j >= n4) j = n4 - 1;       // clamp keeps DMA in-bounds (exact fit at n=1M)
        __builtin_amdgcn_global_load_lds(
            (const GLOBAL_AS void*)(theta4 + j),
            (LDS_AS void*)&ldsT[k * TPB + (w << 6)],
            16, 0, 0);
    }

    // ---- 2) affine into regs — issued in the shadow of the DMAs ----
    float4 av[12];
    #pragma unroll
    for (int k = 0; k < 12; ++k) {
        int j = base4 + k * TPB + t;
        av[k] = affine4[(j < n4) ? j : (n4 - 1)];
    }

    __syncthreads();   // drains vmcnt (incl. LDS-DMA) + barrier

    // ---- 3) MSE from LDS (stride-16B b128 reads: conflict-free) ----
    double mse = 0.0, ortho = 0.0;
    #pragma unroll
    for (int k = 0; k < 12; ++k) {
        if (base4 + k * TPB + t < n4) {
            float4 tv = ldsT[k * TPB + t];
            float dx = tv.x - av[k].x, dy = tv.y - av[k].y;
            float dz = tv.z - av[k].z, dw = tv.w - av[k].w;
            mse += (double)(dx * dx + dy * dy) + (double)(dz * dz + dw * dw);
        }
    }

    // ---- 4) eigensolve: 4 samples/thread. stride-48B b128 reads:
    //         start-banks of 8 consecutive lanes = {0,12,24,4,16,28,8,20}
    //         -> the 8x4 banks tile all 32 exactly: conflict-free. ----
    const int sBase = blockIdx.x * SPB;
    #pragma unroll
    for (int jj = 0; jj < TILES; ++jj) {
        int sl = jj * TPB + t;
        if (sBase + sl < n) {
            float4 a0 = ldsT[3 * sl], a1 = ldsT[3 * sl + 1], a2 = ldsT[3 * sl + 2];
            sample_ortho(a0, a1, a2, ortho);
        }
    }

    // ---- block reduction: wave64 shuffle -> LDS -> per-block partial ----
    #pragma unroll
    for (int off = 32; off > 0; off >>= 1) {
        ortho += __shfl_down(ortho, off);
        mse   += __shfl_down(mse, off);
    }
    __shared__ double so[4], sm[4];
    int lane = t & 63;
    if (lane == 0) { so[w] = ortho; sm[w] = mse; }
    __syncthreads();
    if (t == 0) {
        partial[2 * blockIdx.x]     = so[0] + so[1] + so[2] + so[3];
        partial[2 * blockIdx.x + 1] = sm[0] + sm[1] + sm[2] + sm[3];
    }
}

__global__ __launch_bounds__(256) void finalize_out(
    const double* __restrict__ partial, float* __restrict__ out,
    int nblocks, int n)
{
    double O = 0.0, M = 0.0;
    for (int i = threadIdx.x; i < nblocks; i += 256) {
        O += partial[2 * i];
        M += partial[2 * i + 1];
    }
    #pragma unroll
    for (int off = 32; off > 0; off >>= 1) {
        O += __shfl_down(O, off);
        M += __shfl_down(M, off);
    }
    __shared__ double so[4], sm[4];
    int lane = threadIdx.x & 63, wv = threadIdx.x >> 6;
    if (lane == 0) { so[wv] = O; sm[wv] = M; }
    __syncthreads();
    if (threadIdx.x == 0) {
        double Ot = so[0] + so[1] + so[2] + so[3];
        double Mt = sm[0] + sm[1] + sm[2] + sm[3];
        out[0] = (float)(Ot / (double)n);
        out[1] = (float)(Mt / (12.0 * (double)n));
    }
}

extern "C" void kernel_launch(void* const* d_in, const int* in_sizes, int n_in,
                              void* d_out, int out_size, void* d_ws, size_t ws_size,
                              hipStream_t stream) {
    const float4* theta4  = (const float4*)d_in[0];
    const float4* affine4 = (const float4*)d_in[1];
    double* partial = (double*)d_ws;
    float* out = (float*)d_out;
    int n = in_sizes[0] / 12;           // samples of 3x4

    int blocks = (n + SPB - 1) / SPB;   // 1024 for n = 1M
    theta_loss_main<<<blocks, TPB, 0, stream>>>(theta4, affine4, partial, n);
    finalize_out<<<1, 256, 0, stream>>>(partial, out, blocks, n);
}